// Round 11
// baseline (36.312 us; speedup 1.0000x reference)
//
#include <hip/hip_runtime.h>
#include <hip/hip_bf16.h>
#include <math.h>

// DDRFMixer: out[b,t,d] = sum_n softmax_n(x[b,t,:]·W[n,:]) * x[b,t-off_n,d]
// x: [B,T,D] fp32, W: [7,D] fp32, out: [B,T,D] fp32
// B=4, T=4096, D=1024, offsets = {1,2,4,8,16,32,64}
//
// R10 = R8 (34.4 us) + TWO INDEPENDENT ROWS PER WAVE (interleaved ILP):
//  - Each wave computes rows (r, r+1) in ONE straight-line body. The two
//    dependence chains are independent -> the machine scheduler overlaps
//    row-A's load latency with row-B's compute (and vice versa), doubling
//    per-wave memory parallelism. (R6's serial-strip failed because rows
//    were strictly sequential; R9's upfront loads failed because the
//    compiler sank them. Interleaved chains survive compiler scheduling.)
//  - The two rows share identical W addresses: LDS reads halve per row.
//  - 14 independent DPP reduce chains (VALU pipe).
//  - Grid = 1024 blocks x 512 thr = exactly 4 resident blocks/CU: the whole
//    grid is co-resident in one round -> no block tail.
// Kept: W in LDS, DPP wave reduce, clamp+mask causality, no-max softmax,
// XCD-bijective swizzle, 1-ahead k-pipeline in combine, plain stores.

#define N_TAPS 7
#define DIM 1024
#define T_LEN 4096
#define BLOCK_THREADS 512
#define ROWS_PER_WAVE 2
#define ROWS_PER_BLOCK 16   // 8 waves * 2 rows

// ---- DPP helpers: canonical GCN wave64 sum ----
template <int CTRL>
__device__ __forceinline__ float dpp_mov0(float v) {
    return __builtin_bit_cast(float,
        __builtin_amdgcn_update_dpp(0, __builtin_bit_cast(int, v),
                                    CTRL, 0xf, 0xf, true));
}
__device__ __forceinline__ float wave_sum_bcast(float v) {
    v += dpp_mov0<0x111>(v);   // row_shr:1
    v += dpp_mov0<0x112>(v);   // row_shr:2
    v += dpp_mov0<0x114>(v);   // row_shr:4
    v += dpp_mov0<0x118>(v);   // row_shr:8
    v += dpp_mov0<0x142>(v);   // row_bcast:15
    v += dpp_mov0<0x143>(v);   // row_bcast:31 -> lane63 = total
    return __builtin_bit_cast(float,
        __builtin_amdgcn_readlane(__builtin_bit_cast(int, v), 63));
}

__global__ __launch_bounds__(BLOCK_THREADS) void ddrf_mixer_kernel(
    const float* __restrict__ x,   // [B*T, D]
    const float* __restrict__ W,   // [N_TAPS, D]
    float* __restrict__ out,       // [B*T, D]
    int n_rows)
{
    constexpr int offs[N_TAPS] = {1, 2, 4, 8, 16, 32, 64};

    __shared__ float wlds[N_TAPS * DIM];   // 28 KB

    // ---- stage W into LDS (once per block) ----
    for (int i = threadIdx.x; i < N_TAPS * (DIM / 4); i += BLOCK_THREADS) {
        reinterpret_cast<float4*>(wlds)[i] =
            reinterpret_cast<const float4*>(W)[i];
    }
    __syncthreads();

    // ---- bijective XCD swizzle (gridDim.x = 1024, % 8 == 0) ----
    const int per = gridDim.x >> 3;
    const int wg  = (blockIdx.x & 7) * per + (blockIdx.x >> 3);

    const int wave = threadIdx.x >> 6;
    const int lane = threadIdx.x & 63;
    const int dofs = lane * 4;               // lane's base within each 256-chunk

    const int row0 = wg * ROWS_PER_BLOCK + wave * ROWS_PER_WAVE;
    if (row0 + 1 >= n_rows + 1) return;      // rows row0, row0+1 (n_rows even)

    const float* xrow[ROWS_PER_WAVE];
    int t[ROWS_PER_WAVE];
#pragma unroll
    for (int r = 0; r < ROWS_PER_WAVE; ++r) {
        const int row = row0 + r;
        t[r] = row & (T_LEN - 1);
        xrow[r] = x + (size_t)row * DIM;
    }

    // ---- both rows' xv loads issue first (independent) ----
    float4 xv[ROWS_PER_WAVE][4];
#pragma unroll
    for (int r = 0; r < ROWS_PER_WAVE; ++r)
#pragma unroll
        for (int k = 0; k < 4; ++k)
            xv[r][k] = *reinterpret_cast<const float4*>(xrow[r] + k * 256 + dofs);

    // ---- causal clamp + mask (branch-free) ----
    const float* trow[ROWS_PER_WAVE][N_TAPS];
    float tmask[ROWS_PER_WAVE][N_TAPS];
#pragma unroll
    for (int r = 0; r < ROWS_PER_WAVE; ++r)
#pragma unroll
        for (int n = 0; n < N_TAPS; ++n) {
            const bool ok = (t[r] >= offs[n]);
            trow[r][n]  = xrow[r] - (size_t)(ok ? offs[n] : 0) * DIM;
            tmask[r][n] = ok ? 1.0f : 0.0f;
        }

    // ---- prefetch k=0 taps for both rows (14 loads in flight) ----
    float4 tap[ROWS_PER_WAVE][N_TAPS];
#pragma unroll
    for (int r = 0; r < ROWS_PER_WAVE; ++r)
#pragma unroll
        for (int n = 0; n < N_TAPS; ++n)
            tap[r][n] = *reinterpret_cast<const float4*>(trow[r][n] + dofs);

    // ---- Phase 1: dots vs W. W LDS reads SHARED between the two rows ----
    float p[ROWS_PER_WAVE][N_TAPS];
#pragma unroll
    for (int n = 0; n < N_TAPS; ++n) {
        const float* wrow = &wlds[n * DIM];
        float4 w0 = *reinterpret_cast<const float4*>(wrow + 0 * 256 + dofs);
        float4 w1 = *reinterpret_cast<const float4*>(wrow + 1 * 256 + dofs);
        float4 w2 = *reinterpret_cast<const float4*>(wrow + 2 * 256 + dofs);
        float4 w3 = *reinterpret_cast<const float4*>(wrow + 3 * 256 + dofs);
#pragma unroll
        for (int r = 0; r < ROWS_PER_WAVE; ++r) {
            float s0 = fmaf(xv[r][0].x, w0.x, fmaf(xv[r][0].y, w0.y,
                       fmaf(xv[r][0].z, w0.z, xv[r][0].w * w0.w)));
            float s1 = fmaf(xv[r][1].x, w1.x, fmaf(xv[r][1].y, w1.y,
                       fmaf(xv[r][1].z, w1.z, xv[r][1].w * w1.w)));
            float s2 = fmaf(xv[r][2].x, w2.x, fmaf(xv[r][2].y, w2.y,
                       fmaf(xv[r][2].z, w2.z, xv[r][2].w * w2.w)));
            float s3 = fmaf(xv[r][3].x, w3.x, fmaf(xv[r][3].y, w3.y,
                       fmaf(xv[r][3].z, w3.z, xv[r][3].w * w3.w)));
            p[r][n] = (s0 + s1) + (s2 + s3);
        }
    }

    // ---- DPP wave reduce: 14 independent chains on the VALU pipe ----
#pragma unroll
    for (int r = 0; r < ROWS_PER_WAVE; ++r)
#pragma unroll
        for (int n = 0; n < N_TAPS; ++n)
            p[r][n] = wave_sum_bcast(p[r][n]);

    // ---- softmax (no max subtraction; logits small) + causal mask ----
    float weff[ROWS_PER_WAVE][N_TAPS];
#pragma unroll
    for (int r = 0; r < ROWS_PER_WAVE; ++r) {
        float wn[N_TAPS];
        float wsum = 0.f;
#pragma unroll
        for (int n = 0; n < N_TAPS; ++n) {
            wn[n] = __expf(p[r][n]);
            wsum += wn[n];
        }
        const float inv = 1.0f / wsum;
#pragma unroll
        for (int n = 0; n < N_TAPS; ++n)
            weff[r][n] = wn[n] * inv * tmask[r][n];
    }

    // ---- Phase 2: combine, 1-chunk-ahead pipeline, both rows interleaved ----
#pragma unroll
    for (int k = 0; k < 4; ++k) {
        float4 nxt[ROWS_PER_WAVE][N_TAPS];
        if (k < 3) {
#pragma unroll
            for (int r = 0; r < ROWS_PER_WAVE; ++r)
#pragma unroll
                for (int n = 0; n < N_TAPS; ++n)
                    nxt[r][n] = *reinterpret_cast<const float4*>(
                        trow[r][n] + (k + 1) * 256 + dofs);
        }
#pragma unroll
        for (int r = 0; r < ROWS_PER_WAVE; ++r) {
            float4 a = make_float4(0.f, 0.f, 0.f, 0.f);
#pragma unroll
            for (int n = 0; n < N_TAPS; ++n) {
                a.x = fmaf(weff[r][n], tap[r][n].x, a.x);
                a.y = fmaf(weff[r][n], tap[r][n].y, a.y);
                a.z = fmaf(weff[r][n], tap[r][n].z, a.z);
                a.w = fmaf(weff[r][n], tap[r][n].w, a.w);
            }
            *reinterpret_cast<float4*>(
                out + (size_t)(row0 + r) * DIM + k * 256 + dofs) = a;
        }
        if (k < 3) {
#pragma unroll
            for (int r = 0; r < ROWS_PER_WAVE; ++r)
#pragma unroll
                for (int n = 0; n < N_TAPS; ++n)
                    tap[r][n] = nxt[r][n];
        }
    }
}

extern "C" void kernel_launch(void* const* d_in, const int* in_sizes, int n_in,
                              void* d_out, int out_size, void* d_ws, size_t ws_size,
                              hipStream_t stream) {
    const float* x = (const float*)d_in[0];   // [B,T,D] fp32
    const float* W = (const float*)d_in[1];   // [N_TAPS,D] fp32
    float* out = (float*)d_out;               // [B,T,D] fp32

    const int n_rows   = in_sizes[0] / DIM;          // B*T = 16384
    const int n_blocks = n_rows / ROWS_PER_BLOCK;    // 1024 (divisible by 8)

    ddrf_mixer_kernel<<<n_blocks, BLOCK_THREADS, 0, stream>>>(x, W, out, n_rows);
}